// Round 1
// baseline (6240.163 us; speedup 1.0000x reference)
//
#include <hip/hip_runtime.h>
#include <hip/hip_bf16.h>
#include <stdint.h>

typedef unsigned short u16;
typedef unsigned int   u32;
typedef __attribute__((ext_vector_type(4))) float f32x4;
typedef __attribute__((ext_vector_type(8))) short bf16x8;

#define SENT 0xAAAAAAAAu

static __device__ __forceinline__ u16 f2bf(float x) {
  union { float f; u32 u; } v; v.f = x;
  u32 r = v.u + 0x7FFFu + ((v.u >> 16) & 1u);
  return (u16)(r >> 16);
}
static __device__ __forceinline__ float bf2f(u16 b) {
  union { u32 u; float f; } v; v.u = ((u32)b) << 16;
  return v.f;
}

// ---------------- small prep kernels ----------------

__global__ void split_hl(const float* __restrict__ in, u16* __restrict__ hi,
                         u16* __restrict__ lo, int n) {
  int i = blockIdx.x * 256 + threadIdx.x;
  if (i < n) {
    float v = in[i];
    u16 h = f2bf(v);
    hi[i] = h;
    lo[i] = f2bf(v - bf2f(h));
  }
}

__global__ void embed_split(const int* __restrict__ x, const float* __restrict__ emb,
                            u16* __restrict__ hi, u16* __restrict__ lo) {
  int gid = blockIdx.x * 256 + threadIdx.x;   // 4096*512 total
  int bt = gid >> 9, d = gid & 511;
  float v = emb[(size_t)x[bt] * 512 + d];
  u16 h = f2bf(v);
  hi[gid] = h;
  lo[gid] = f2bf(v - bf2f(h));
}

__global__ void fill_sent(u32* __restrict__ p, int n) {
  int i = blockIdx.x * 256 + threadIdx.x;
  if (i < n) p[i] = SENT;
}

// Pack Whh into per-lane MFMA B-fragment order, hi/lo bf16 split.
// flat tid = ((((((lyr*2+d)*16+q)*4+w)*8+kt)*2+pass)*64+lane)*4+dw
__global__ void lstm_wpack(const float* __restrict__ Whh, u32* __restrict__ wp) {
  int tid = blockIdx.x * 256 + threadIdx.x;   // 1,048,576 total
  int dw   = tid & 3;
  int lane = (tid >> 2) & 63;
  int pass = (tid >> 8) & 1;
  int kt   = (tid >> 9) & 7;
  int w    = (tid >> 12) & 3;
  int q    = (tid >> 14) & 15;
  int d    = (tid >> 18) & 1;
  int lyr  = (tid >> 19) & 1;
  int row = w * 256 + q * 16 + (lane & 15);
  int k   = kt * 32 + (lane >> 4) * 8 + dw * 2;
  const float* src = Whh + (((size_t)(lyr * 2 + d) * 1024 + row) * 256);
  float w0 = src[k], w1 = src[k + 1];
  u16 h0 = f2bf(w0), h1 = f2bf(w1);
  u32 out;
  if (pass == 0) out = (u32)h0 | ((u32)h1 << 16);
  else {
    u16 l0 = f2bf(w0 - bf2f(h0)), l1 = f2bf(w1 - bf2f(h1));
    out = (u32)l0 | ((u32)l1 << 16);
  }
  wp[tid] = out;
}

__global__ void resadd_split(const float* __restrict__ a, const float* __restrict__ b,
                             u16* __restrict__ hi, u16* __restrict__ lo, int n) {
  int i = blockIdx.x * 256 + threadIdx.x;
  if (i < n) {
    float v = a[i] + b[i];
    u16 h = f2bf(v);
    hi[i] = h;
    lo[i] = f2bf(v - bf2f(h));
  }
}

// ---------------- bf16x3 MFMA GEMM: C = A * B^T + bias ----------------
// A: M x K (row-major, hi/lo bf16), B: N x K (row-major weights, hi/lo bf16)
template<int RELU, int WF32, int WHL>
__global__ __launch_bounds__(256) void gemm_x3(
    const u16* __restrict__ Ahi, const u16* __restrict__ Alo,
    const u16* __restrict__ Bhi, const u16* __restrict__ Blo,
    const float* __restrict__ bias,
    float* __restrict__ Cf, u16* __restrict__ Chi, u16* __restrict__ Clo,
    int M, int N, int Kd)
{
  __shared__ u16 As_hi[128][40], As_lo[128][40], Bs_hi[128][40], Bs_lo[128][40];
  int t = threadIdx.x;
  int bm = blockIdx.x * 128, bn = blockIdx.y * 128;
  int l = t & 63, wid = t >> 6;
  int wy = wid >> 1, wx = wid & 1;
  f32x4 acc[4][4];
#pragma unroll
  for (int i = 0; i < 4; i++)
#pragma unroll
    for (int j = 0; j < 4; j++) acc[i][j] = (f32x4){0.f, 0.f, 0.f, 0.f};

  for (int kt = 0; kt < Kd; kt += 32) {
    __syncthreads();
#pragma unroll
    for (int cc = 0; cc < 2; cc++) {
      int c = t + cc * 256;
      int row = c >> 2, k8 = (c & 3) << 3;
      *(uint4*)&As_hi[row][k8] = *(const uint4*)(Ahi + (size_t)(bm + row) * Kd + kt + k8);
      *(uint4*)&As_lo[row][k8] = *(const uint4*)(Alo + (size_t)(bm + row) * Kd + kt + k8);
      *(uint4*)&Bs_hi[row][k8] = *(const uint4*)(Bhi + (size_t)(bn + row) * Kd + kt + k8);
      *(uint4*)&Bs_lo[row][k8] = *(const uint4*)(Blo + (size_t)(bn + row) * Kd + kt + k8);
    }
    __syncthreads();
    bf16x8 bh[4], bl[4];
    int k8 = (l >> 4) << 3;
#pragma unroll
    for (int ni = 0; ni < 4; ni++) {
      int r = wx * 64 + ni * 16 + (l & 15);
      bh[ni] = *(const bf16x8*)&Bs_hi[r][k8];
      bl[ni] = *(const bf16x8*)&Bs_lo[r][k8];
    }
#pragma unroll
    for (int mi = 0; mi < 4; mi++) {
      int r = wy * 64 + mi * 16 + (l & 15);
      bf16x8 ah = *(const bf16x8*)&As_hi[r][k8];
      bf16x8 al = *(const bf16x8*)&As_lo[r][k8];
#pragma unroll
      for (int ni = 0; ni < 4; ni++) {
        acc[mi][ni] = __builtin_amdgcn_mfma_f32_16x16x32_bf16(ah, bh[ni], acc[mi][ni], 0, 0, 0);
        acc[mi][ni] = __builtin_amdgcn_mfma_f32_16x16x32_bf16(ah, bl[ni], acc[mi][ni], 0, 0, 0);
        acc[mi][ni] = __builtin_amdgcn_mfma_f32_16x16x32_bf16(al, bh[ni], acc[mi][ni], 0, 0, 0);
      }
    }
  }
#pragma unroll
  for (int ni = 0; ni < 4; ni++) {
    int col = bn + wx * 64 + ni * 16 + (l & 15);
    float bv = bias ? bias[col] : 0.f;
#pragma unroll
    for (int mi = 0; mi < 4; mi++) {
#pragma unroll
      for (int r = 0; r < 4; r++) {
        int row = bm + wy * 64 + mi * 16 + (l >> 4) * 4 + r;
        float v = acc[mi][ni][r] + bv;
        if (RELU) v = fmaxf(v, 0.f);
        size_t o = (size_t)row * N + col;
        if (WF32) Cf[o] = v;
        if (WHL) { u16 h = f2bf(v); Chi[o] = h; Clo[o] = f2bf(v - bf2f(h)); }
      }
    }
  }
}

// ---------------- LSTM recurrence ----------------
// grid = 32 blocks: dir = bid>>4, q = bid&15 (unit group of 16 units).
// 256 threads = 4 waves; wave w owns gate w (N-tile = rows w*256+q*16..+16).
// Weights (hi+lo bf16) resident in VGPRs as B-fragments. Per-step cross-WG
// h exchange via sentinel-validated dwords (agent-scope atomics, LLC).
__global__ __launch_bounds__(256, 1) void lstm_rec(
    const u32* __restrict__ wpack_l,
    const float* __restrict__ xw_f, const float* __restrict__ xw_b,
    u32* __restrict__ hex_l,
    u16* __restrict__ out_hi, u16* __restrict__ out_lo, float* __restrict__ out_f)
{
  int bid = blockIdx.x;
  int dir = bid >> 4, q = bid & 15;
  int tid = threadIdx.x;
  int l = tid & 63, w = tid >> 6;
  int b15 = l & 15, k4 = (l >> 4) * 4;
  const float* xw = dir ? xw_b : xw_f;
  u32* hexd = hex_l + (size_t)dir * (1u << 20);   // [hi 512K dwords][lo 512K dwords]

  // load resident W fragments
  bf16x8 wfrag[8][2];
  {
    const u32* wb = wpack_l + (((size_t)(dir * 16 + q) * 4 + w) * 16) * 256;
#pragma unroll
    for (int kt = 0; kt < 8; kt++)
#pragma unroll
      for (int p = 0; p < 2; p++) {
        union { uint4 q4; bf16x8 v; } u;
        u.q4 = *(const uint4*)(wb + ((kt * 2 + p) * 64 + l) * 4);
        wfrag[kt][p] = u.v;
      }
  }

  __shared__ float gbuf[4][16][17];
  __shared__ u16 hbH[16][17], hbL[16][17];
  int gu = tid & 15, gb = tid >> 4;   // gates thread -> (unit, batch)
  float c_state = 0.f;

  for (int s = 0; s < 256; s++) {
    int tpos = dir ? (255 - s) : s;
    // xw C-fragment (bias already folded in by the GEMM)
    int col = w * 256 + q * 16 + b15;
    float x0 = xw[((size_t)((k4 + 0) * 256 + tpos)) * 1024 + col];
    float x1 = xw[((size_t)((k4 + 1) * 256 + tpos)) * 1024 + col];
    float x2 = xw[((size_t)((k4 + 2) * 256 + tpos)) * 1024 + col];
    float x3 = xw[((size_t)((k4 + 3) * 256 + tpos)) * 1024 + col];
    f32x4 aH = {x0, x1, x2, x3};
    f32x4 aL1 = {0.f, 0.f, 0.f, 0.f};
    f32x4 aL2 = {0.f, 0.f, 0.f, 0.f};

    if (s > 0) {
      u32 adh[8][4], adl[8][4];
      const u32* ah = hexd + ((size_t)(s - 1) * 16 + b15) * 128;
      const u32* al = ah + (1u << 19);
      for (int it = 0; it < (1 << 22); ++it) {
        bool ok = true;
#pragma unroll
        for (int kt = 0; kt < 8; kt++)
#pragma unroll
          for (int d4 = 0; d4 < 4; d4++) {
            int idx = kt * 16 + k4 + d4;
            adh[kt][d4] = __hip_atomic_load(ah + idx, __ATOMIC_RELAXED, __HIP_MEMORY_SCOPE_AGENT);
            adl[kt][d4] = __hip_atomic_load(al + idx, __ATOMIC_RELAXED, __HIP_MEMORY_SCOPE_AGENT);
            ok = ok && (adh[kt][d4] != SENT) && (adl[kt][d4] != SENT);
          }
        if (__all(ok)) break;
      }
#pragma unroll
      for (int kt = 0; kt < 8; kt++) {
        union { u32 u[4]; bf16x8 v; } fh, fl;
#pragma unroll
        for (int d4 = 0; d4 < 4; d4++) { fh.u[d4] = adh[kt][d4]; fl.u[d4] = adl[kt][d4]; }
        aH  = __builtin_amdgcn_mfma_f32_16x16x32_bf16(fh.v, wfrag[kt][0], aH, 0, 0, 0);
        aL1 = __builtin_amdgcn_mfma_f32_16x16x32_bf16(fh.v, wfrag[kt][1], aL1, 0, 0, 0);
        aL2 = __builtin_amdgcn_mfma_f32_16x16x32_bf16(fl.v, wfrag[kt][0], aL2, 0, 0, 0);
      }
    }
#pragma unroll
    for (int r = 0; r < 4; r++)
      gbuf[w][b15][k4 + r] = aH[r] + aL1[r] + aL2[r];
    __syncthreads();

    // gates (thread = (unit gu, batch gb))
    float gi = gbuf[0][gu][gb], gf = gbuf[1][gu][gb];
    float gg = gbuf[2][gu][gb], go = gbuf[3][gu][gb];
    float si = 1.f / (1.f + __expf(-gi));
    float sf = 1.f / (1.f + __expf(-gf));
    float so = 1.f / (1.f + __expf(-go));
    float eg = __expf(2.f * gg);
    float tg = (eg - 1.f) / (eg + 1.f);
    c_state = sf * c_state + si * tg;
    float ec = __expf(2.f * c_state);
    float th = (ec - 1.f) / (ec + 1.f);
    float h = so * th;
    u16 hb = f2bf(h);
    u16 lb = f2bf(h - bf2f(hb));
    hbH[gu][gb] = hb;
    hbL[gu][gb] = lb;
    size_t oo = (((size_t)gb * 256 + tpos) * 512) + dir * 256 + q * 16 + gu;
    out_hi[oo] = hb;
    out_lo[oo] = lb;
    if (out_f) out_f[oo] = h;
    __syncthreads();

    // publish exchange dwords (self-validating, agent scope)
    {
      int t2 = tid & 127;
      int bb = t2 & 15, up = t2 >> 4;
      u32* dst = hexd + ((size_t)s * 16 + bb) * 128 + (q * 8 + up);
      if (tid < 128) {
        u32 bits = (u32)hbH[up * 2][bb] | ((u32)hbH[up * 2 + 1][bb] << 16);
        if (bits == SENT) bits ^= 1u;
        __hip_atomic_store(dst, bits, __ATOMIC_RELAXED, __HIP_MEMORY_SCOPE_AGENT);
      } else {
        u32 bits = (u32)hbL[up * 2][bb] | ((u32)hbL[up * 2 + 1][bb] << 16);
        if (bits == SENT) bits ^= 1u;
        __hip_atomic_store(dst + (1u << 19), bits, __ATOMIC_RELAXED, __HIP_MEMORY_SCOPE_AGENT);
      }
    }
  }
}

// ---------------- final small GEMM (fp32 exact): em = h256 * out_W^T + out_b
__global__ __launch_bounds__(256) void out_gemm(const float* __restrict__ h,
                                                const float* __restrict__ Wo,
                                                const float* __restrict__ bo,
                                                float* __restrict__ em)
{
  int t = threadIdx.x;
  if (t >= 160) return;
  int r = t / 20, j = t - r * 20;
  int bt = blockIdx.x * 8 + r;
  const float* hr = h + (size_t)bt * 256;
  const float* wr = Wo + j * 256;
  float acc = 0.f;
#pragma unroll 4
  for (int k = 0; k < 256; k++) acc += hr[k] * wr[k];
  em[(size_t)bt * 20 + j] = acc + bo[j];
}

// ---------------- Viterbi ----------------
__global__ __launch_bounds__(192) void viterbi(const float* __restrict__ em,
                                               const float* __restrict__ cstart,
                                               const float* __restrict__ cend,
                                               const float* __restrict__ ctrans,
                                               float* __restrict__ tago)
{
  __shared__ float sc[8][20];
  __shared__ float tl[400];
  __shared__ unsigned char hist[255][8][20];
  int t = threadIdx.x;
  for (int i = t; i < 400; i += 192) tl[i] = ctrans[i];
  int bl = t / 20, j = t - bl * 20;
  bool act = (t < 160);
  int b = blockIdx.x * 8 + bl;
  if (act) sc[bl][j] = cstart[j] + em[((size_t)b * 256) * 20 + j];
  __syncthreads();
  for (int step = 1; step < 256; step++) {
    float best = -1e30f; int bi = 0;
    if (act) {
      best = sc[bl][0] + tl[j]; bi = 0;
#pragma unroll
      for (int i = 1; i < 20; i++) {
        float v = sc[bl][i] + tl[i * 20 + j];
        if (v > best) { best = v; bi = i; }
      }
      hist[step - 1][bl][j] = (unsigned char)bi;
    }
    __syncthreads();
    if (act) sc[bl][j] = best + em[((size_t)b * 256 + step) * 20 + j];
    __syncthreads();
  }
  if (act && j == 0) {
    float best = sc[bl][0] + cend[0]; int bj = 0;
    for (int i = 1; i < 20; i++) {
      float v = sc[bl][i] + cend[i];
      if (v > best) { best = v; bj = i; }
    }
    int tag = bj;
    tago[(size_t)b * 256 + 255] = (float)tag;
    for (int step = 254; step >= 0; step--) {
      tag = hist[step][bl][tag];
      tago[(size_t)b * 256 + step] = (float)tag;
    }
  }
}

// ---------------- launch ----------------
extern "C" void kernel_launch(void* const* d_in, const int* in_sizes, int n_in,
                              void* d_out, int out_size, void* d_ws, size_t ws_size,
                              hipStream_t stream)
{
  const int*   x   = (const int*)  d_in[0];
  const float* emb = (const float*)d_in[1];
  const float* Wih = (const float*)d_in[2];
  const float* Whh = (const float*)d_in[3];
  const float* lb  = (const float*)d_in[4];
  const float* fW1 = (const float*)d_in[5];
  const float* fb1 = (const float*)d_in[6];
  const float* fW2 = (const float*)d_in[7];
  const float* fb2 = (const float*)d_in[8];
  const float* foW = (const float*)d_in[9];
  const float* fob = (const float*)d_in[10];
  const float* oW  = (const float*)d_in[11];
  const float* ob  = (const float*)d_in[12];
  const float* cst = (const float*)d_in[13];
  const float* cen = (const float*)d_in[14];
  const float* ctr = (const float*)d_in[15];

  const size_t MB = 1u << 20;
  if (ws_size < 100 * MB) return;
  char* ws = (char*)d_ws;

  u16* embHi = (u16*)(ws + 0 * MB);
  u16* embLo = (u16*)(ws + 4 * MB);
  u16* l1Hi  = (u16*)(ws + 8 * MB);
  u16* l1Lo  = (u16*)(ws + 12 * MB);
  float* l2F = (float*)(ws + 16 * MB);
  u16* l2Hi  = (u16*)(ws + 24 * MB);
  u16* l2Lo  = (u16*)(ws + 28 * MB);
  float* xwF = (float*)(ws + 32 * MB);
  float* xwB = (float*)(ws + 48 * MB);
  u32* hexB  = (u32*)(ws + 64 * MB);    // 16 MB: 2 layers x (2 dirs x 4MB)
  u32* wpck  = (u32*)(ws + 80 * MB);    // 4 MB
  u16* wihHi = (u16*)(ws + 84 * MB);
  u16* wihLo = (u16*)(ws + 88 * MB);
  u16* fw1Hi = (u16*)(ws + 92 * MB);
  u16* fw1Lo = (u16*)(ws + 93 * MB);
  u16* fw2Hi = (u16*)(ws + 94 * MB);
  u16* fw2Lo = (u16*)(ws + 95 * MB);
  u16* ffoHi = (u16*)(ws + 96 * MB);
  u16* ffoLo = (u16*)(ws + 96 * MB + 512 * 1024);
  // aliases into xw regions (free after the recurrent layers)
  u16* t1Hi = (u16*)xwF;
  u16* t1Lo = (u16*)((char*)xwF + 4 * MB);
  u16* t2Hi = (u16*)xwB;
  u16* t2Lo = (u16*)((char*)xwB + 4 * MB);
  float* h2F = (float*)((char*)xwB + 8 * MB);
  u16* sumHi = (u16*)((char*)xwF + 8 * MB);
  u16* sumLo = (u16*)((char*)xwF + 12 * MB);
  float* h256F = (float*)xwF;

  float* em   = (float*)d_out;
  float* tago = (float*)d_out + 81920;

  dim3 blk(256);

  // weight prep
  split_hl<<<8192, blk, 0, stream>>>(Wih, wihHi, wihLo, 4 * 1024 * 512);
  split_hl<<<2048, blk, 0, stream>>>(fW1, fw1Hi, fw1Lo, 2 * 512 * 512);
  split_hl<<<2048, blk, 0, stream>>>(fW2, fw2Hi, fw2Lo, 2 * 512 * 512);
  split_hl<<<512,  blk, 0, stream>>>(foW, ffoHi, ffoLo, 256 * 512);
  lstm_wpack<<<4096, blk, 0, stream>>>(Whh, wpck);
  embed_split<<<8192, blk, 0, stream>>>(x, emb, embHi, embLo);
  fill_sent<<<16384, blk, 0, stream>>>(hexB, 4 * 1024 * 1024);

  // layer 0
  gemm_x3<0,1,0><<<dim3(32, 8), blk, 0, stream>>>(embHi, embLo,
      wihHi + 0 * 524288, wihLo + 0 * 524288, lb + 0 * 1024,
      xwF, nullptr, nullptr, 4096, 1024, 512);
  gemm_x3<0,1,0><<<dim3(32, 8), blk, 0, stream>>>(embHi, embLo,
      wihHi + 1 * 524288, wihLo + 1 * 524288, lb + 1 * 1024,
      xwB, nullptr, nullptr, 4096, 1024, 512);
  lstm_rec<<<32, blk, 0, stream>>>(wpck, xwF, xwB, hexB, l1Hi, l1Lo, nullptr);

  // layer 1
  gemm_x3<0,1,0><<<dim3(32, 8), blk, 0, stream>>>(l1Hi, l1Lo,
      wihHi + 2 * 524288, wihLo + 2 * 524288, lb + 2 * 1024,
      xwF, nullptr, nullptr, 4096, 1024, 512);
  gemm_x3<0,1,0><<<dim3(32, 8), blk, 0, stream>>>(l1Hi, l1Lo,
      wihHi + 3 * 524288, wihLo + 3 * 524288, lb + 3 * 1024,
      xwB, nullptr, nullptr, 4096, 1024, 512);
  lstm_rec<<<32, blk, 0, stream>>>(wpck + (1u << 19), xwF, xwB,
      hexB + (2u << 20), l2Hi, l2Lo, l2F);

  // FF stack
  gemm_x3<1,0,1><<<dim3(32, 4), blk, 0, stream>>>(l2Hi, l2Lo,
      fw1Hi + 0, fw1Lo + 0, fb1 + 0, nullptr, t1Hi, t1Lo, 4096, 512, 512);
  gemm_x3<0,0,1><<<dim3(32, 4), blk, 0, stream>>>(t1Hi, t1Lo,
      fw2Hi + 0, fw2Lo + 0, fb2 + 0, nullptr, t2Hi, t2Lo, 4096, 512, 512);
  gemm_x3<1,0,1><<<dim3(32, 4), blk, 0, stream>>>(t2Hi, t2Lo,
      fw1Hi + 262144, fw1Lo + 262144, fb1 + 512, nullptr, t1Hi, t1Lo, 4096, 512, 512);
  gemm_x3<0,1,0><<<dim3(32, 4), blk, 0, stream>>>(t1Hi, t1Lo,
      fw2Hi + 262144, fw2Lo + 262144, fb2 + 512, h2F, nullptr, nullptr, 4096, 512, 512);
  resadd_split<<<8192, blk, 0, stream>>>(h2F, l2F, sumHi, sumLo, 4096 * 512);
  gemm_x3<0,1,0><<<dim3(32, 2), blk, 0, stream>>>(sumHi, sumLo,
      ffoHi, ffoLo, fob, h256F, nullptr, nullptr, 4096, 256, 512);

  out_gemm<<<512, blk, 0, stream>>>(h256F, oW, ob, em);
  viterbi<<<2, dim3(192), 0, stream>>>(em, cst, cen, ctr, tago);
}